// Round 1
// baseline (537.230 us; speedup 1.0000x reference)
//
#include <hip/hip_runtime.h>

using short8 = __attribute__((ext_vector_type(8))) short;
using f32x4  = __attribute__((ext_vector_type(4))) float;

__device__ __forceinline__ short f2bf(float f){
  unsigned u = __float_as_uint(f);
  unsigned r = (u + 0x7FFFu + ((u >> 16) & 1u)) >> 16;
  return (short)r;
}

// ---------------- depthwise 3x3 stride-1 (q) + stats partials ----------------
__global__ __launch_bounds__(384) void k_dw1(const float* __restrict__ in, const float* __restrict__ wq,
                                             short* __restrict__ dqb, float2* __restrict__ part){
  int bid = blockIdx.x; int b = bid / 56, oh = bid % 56; int t = threadIdx.x;
  int c = t % 192;
  float w[9];
#pragma unroll
  for(int i=0;i<9;i++) w[i] = wq[i*192 + c];
  const float* inb = in + (size_t)b*56*56*192;
  float lsum = 0.f, lsq = 0.f;
  size_t orow = ((size_t)b*3136 + (size_t)oh*56)*192;
#pragma unroll 1
  for(int i=0;i<28;i++){
    int e = t + 384*i; int ow = e / 192;
    float acc = 0.f;
#pragma unroll
    for(int kh=0;kh<3;kh++){
      int ih = oh + kh - 1;
      if(ih < 0 || ih >= 56) continue;
      const float* rp = inb + (size_t)ih*56*192;
#pragma unroll
      for(int kw=0;kw<3;kw++){
        int iw = ow + kw - 1;
        if(iw >= 0 && iw < 56) acc = fmaf(rp[iw*192 + c], w[kh*3+kw], acc);
      }
    }
    dqb[orow + e] = f2bf(acc);
    lsum += acc; lsq = fmaf(acc, acc, lsq);
  }
  __shared__ float red[2][384];
  red[0][t] = lsum; red[1][t] = lsq;
  __syncthreads();
  if(t < 192){
    float2 o; o.x = lsum + red[0][t+192]; o.y = lsq + red[1][t+192];
    part[(size_t)bid*192 + t] = o;
  }
}

// ---------------- depthwise 3x3 stride-2 (k and v) + stats partials ----------------
__global__ __launch_bounds__(384) void k_dw2(const float* __restrict__ in, const float* __restrict__ wk,
                                             const float* __restrict__ wv, short* __restrict__ dkb,
                                             short* __restrict__ dvb, float2* __restrict__ partk,
                                             float2* __restrict__ partv){
  int bid = blockIdx.x; int b = bid / 28, oh = bid % 28; int t = threadIdx.x;
  int c = t % 192;
  float wkr[9], wvr[9];
#pragma unroll
  for(int i=0;i<9;i++){ wkr[i] = wk[i*192 + c]; wvr[i] = wv[i*192 + c]; }
  const float* inb = in + (size_t)b*56*56*192;
  float ksum=0.f, ksq=0.f, vsum=0.f, vsq=0.f;
  size_t orow = ((size_t)b*784 + (size_t)oh*28)*192;
#pragma unroll 1
  for(int i=0;i<14;i++){
    int e = t + 384*i; int ow = e / 192;
    float ak = 0.f, av = 0.f;
#pragma unroll
    for(int kh=0;kh<3;kh++){
      int ih = 2*oh + kh;                  // SAME stride-2: pad_lo = 0
      if(ih >= 56) continue;
      const float* rp = inb + (size_t)ih*56*192;
#pragma unroll
      for(int kw=0;kw<3;kw++){
        int iw = 2*ow + kw;
        if(iw < 56){
          float x = rp[iw*192 + c];
          ak = fmaf(x, wkr[kh*3+kw], ak);
          av = fmaf(x, wvr[kh*3+kw], av);
        }
      }
    }
    dkb[orow + e] = f2bf(ak); dvb[orow + e] = f2bf(av);
    ksum += ak; ksq = fmaf(ak, ak, ksq);
    vsum += av; vsq = fmaf(av, av, vsq);
  }
  __shared__ float red[4][384];
  red[0][t]=ksum; red[1][t]=ksq; red[2][t]=vsum; red[3][t]=vsq;
  __syncthreads();
  if(t < 192){
    float2 a; a.x = ksum + red[0][t+192]; a.y = ksq + red[1][t+192];
    partk[(size_t)bid*192 + t] = a;
    float2 o; o.x = vsum + red[2][t+192]; o.y = vsq + red[3][t+192];
    partv[(size_t)bid*192 + t] = o;
  }
}

// ---------------- finalize stats; fold BN + scale into transposed bf16 weights ----------------
__global__ __launch_bounds__(192) void k_fin(const float2* __restrict__ pq, const float2* __restrict__ pk,
                                             const float2* __restrict__ pv,
                                             const float* __restrict__ sq, const float* __restrict__ oq,
                                             const float* __restrict__ sk, const float* __restrict__ ok,
                                             const float* __restrict__ sv, const float* __restrict__ ov,
                                             const float* __restrict__ pwq, const float* __restrict__ pwk,
                                             const float* __restrict__ pwv, const float* __restrict__ wout,
                                             short* __restrict__ Wt, float* __restrict__ bias){
  int p = blockIdx.x, t = threadIdx.x;
  __shared__ float aS[192], bS[192];
  if(p < 3){
    const float2* part = (p==0)?pq:((p==1)?pk:pv);
    int nb = (p==0)?896:448;
    float N = (p==0)?50176.f:12544.f;
    const float* sc = (p==0)?sq:((p==1)?sk:sv);
    const float* of = (p==0)?oq:((p==1)?ok:ov);
    float s=0.f, q2=0.f;
#pragma unroll 4
    for(int i=0;i<nb;i++){ float2 v = part[(size_t)i*192 + t]; s += v.x; q2 += v.y; }
    float mean = s / N;
    float var  = q2 / N - mean*mean;
    float a  = rsqrtf(var + 1e-5f) * sc[t];
    float bv = of[t] - mean*a;
    aS[t] = a; bS[t] = bv;
    __syncthreads();
    const float* pw = (p==0)?pwq:((p==1)?pwk:pwv);
    float qs = (p==0) ? 0.125f : 1.0f;   // fold 1/sqrt(64) into q
    float bacc = 0.f;
    for(int cc=0; cc<192; cc++){
      float wv_ = pw[cc*192 + t];
      bacc = fmaf(bS[cc], wv_, bacc);
      Wt[((size_t)p*192 + t)*192 + cc] = f2bf(aS[cc]*wv_*qs);
    }
    bias[p*192 + t] = bacc * qs;
  } else {
    for(int cc=0; cc<192; cc++) Wt[((size_t)3*192 + t)*192 + cc] = f2bf(wout[cc*192 + t]);
    bias[3*192 + t] = 0.f;
  }
}

// ---------------- bf16 MFMA GEMM: [M,192] @ (Wt^T) + bias; per-mode epilogue ----------------
template<int MODE>
__global__ __launch_bounds__(256) void k_gemm(const short* __restrict__ A, const short* __restrict__ Wt,
                                              const float* __restrict__ bias, void* __restrict__ outp){
  int w = threadIdx.x >> 6, L = threadIdx.x & 63, l16 = L & 15, h4 = L >> 4;
  int row0 = blockIdx.x*64 + w*16;
  short8 af[6];
  const short8* arow = (const short8*)(A + (size_t)(row0 + l16)*192);
#pragma unroll
  for(int kf=0;kf<6;kf++) af[kf] = arow[kf*4 + h4];
  f32x4 acc[12];
#pragma unroll
  for(int i=0;i<12;i++) acc[i] = f32x4{0.f,0.f,0.f,0.f};
#pragma unroll
  for(int nt=0;nt<12;nt++){
    const short8* wrow = (const short8*)(Wt + (size_t)(nt*16 + l16)*192);
#pragma unroll
    for(int kf=0;kf<6;kf++){
      short8 bf = wrow[kf*4 + h4];
      acc[nt] = __builtin_amdgcn_mfma_f32_16x16x32_bf16(af[kf], bf, acc[nt], 0,0,0);
    }
  }
#pragma unroll
  for(int nt=0;nt<12;nt++){
    int col = nt*16 + l16;
    float bv = (MODE==3) ? 0.f : bias[col];
#pragma unroll
    for(int r=0;r<4;r++){
      int row = row0 + h4*4 + r;
      float v = acc[nt][r] + bv;
      if(MODE==0){
        ((short*)outp)[(size_t)row*192 + col] = f2bf(v);
      } else if(MODE==1){
        int b = row/784, kk = row - b*784;
        ((short*)outp)[((size_t)b*832 + kk)*192 + col] = f2bf(v);
      } else if(MODE==2){
        int b = row/784, kk = row - b*784;
        ((short*)outp)[((size_t)(b*192 + col))*832 + kk] = f2bf(v);
      } else {
        ((float*)outp)[(size_t)row*192 + col] = v;
      }
    }
  }
}

// ---------------- fused talking-heads attention ----------------
__global__ __launch_bounds__(256) void k_attn(const short* __restrict__ qb, const short* __restrict__ kb,
                                              const short* __restrict__ vt, const float* __restrict__ pre,
                                              const float* __restrict__ post, short* __restrict__ sb){
  __shared__ __align__(16) short sKV[13824];          // K as [64][200] (padded) / V as [192][72] (padded)
  __shared__ __align__(16) short sP[4][3][16][72];    // per-wave post-mixed P (bf16)
  int bx = blockIdx.x; int b = bx / 49, lt = bx - b*49;
  int tid = threadIdx.x; int w = tid >> 6, L = tid & 63, l16 = L & 15, h4 = L >> 4;
  int lw = lt*64 + w*16;
  float pm[3][3], po[3][3];
#pragma unroll
  for(int h=0;h<3;h++)
#pragma unroll
    for(int g=0;g<3;g++){ pm[h][g] = pre[h*3+g]; po[h][g] = post[h*3+g]; }

  short8 qf[3][2];
  const short8* qrow = (const short8*)(qb + ((size_t)b*3136 + lw + l16)*192);
#pragma unroll
  for(int h=0;h<3;h++)
#pragma unroll
    for(int kf=0;kf<2;kf++) qf[h][kf] = qrow[h*8 + kf*4 + h4];

  float Zp[3][4];
#pragma unroll
  for(int g=0;g<3;g++)
#pragma unroll
    for(int r=0;r<4;r++) Zp[g][r] = 0.f;

  // ---- pass A: compute Z per (g,row) ----
#pragma unroll 1
  for(int ks=0; ks<13; ks++){
    __syncthreads();
    {
      const uint4* src = (const uint4*)(kb + ((size_t)b*832 + ks*64)*192);
#pragma unroll
      for(int j=0;j<6;j++){
        int f = tid + 256*j;
        int row = f / 24, cu = f - row*24;
        *(uint4*)&sKV[row*200 + cu*8] = src[f];
      }
    }
    __syncthreads();
    f32x4 acc[3][4];
#pragma unroll
    for(int h=0;h<3;h++)
#pragma unroll
      for(int nt=0;nt<4;nt++) acc[h][nt] = f32x4{0.f,0.f,0.f,0.f};
#pragma unroll
    for(int h=0;h<3;h++)
#pragma unroll
      for(int kf=0;kf<2;kf++){
        short8 aq = qf[h][kf];
#pragma unroll
        for(int nt=0;nt<4;nt++){
          short8 bk = *(const short8*)&sKV[(nt*16 + l16)*200 + h*64 + kf*32 + h4*8];
          acc[h][nt] = __builtin_amdgcn_mfma_f32_16x16x32_bf16(aq, bk, acc[h][nt], 0,0,0);
        }
      }
    bool full = (ks < 12);
#pragma unroll
    for(int nt=0;nt<4;nt++){
      bool valid = full || (ks*64 + nt*16 + l16) < 784;
#pragma unroll
      for(int r=0;r<4;r++){
        float s0 = acc[0][nt][r], s1 = acc[1][nt][r], s2 = acc[2][nt][r];
#pragma unroll
        for(int g=0;g<3;g++){
          float sm = fmaf(pm[0][g], s0, fmaf(pm[1][g], s1, pm[2][g]*s2));
          float e = valid ? __expf(sm) : 0.f;
          Zp[g][r] += e;
        }
      }
    }
  }
#pragma unroll
  for(int g=0;g<3;g++)
#pragma unroll
    for(int r=0;r<4;r++){
      float z = Zp[g][r];
      z += __shfl_xor(z, 1); z += __shfl_xor(z, 2); z += __shfl_xor(z, 4); z += __shfl_xor(z, 8);
      Zp[g][r] = 1.f / z;
    }

  // ---- pass B: normalized post-mixed P, PV accumulate ----
  f32x4 U[3][4];
#pragma unroll
  for(int g=0;g<3;g++)
#pragma unroll
    for(int nt=0;nt<4;nt++) U[g][nt] = f32x4{0.f,0.f,0.f,0.f};

#pragma unroll 1
  for(int ks=0; ks<13; ks++){
    __syncthreads();
    {
      const uint4* src = (const uint4*)(kb + ((size_t)b*832 + ks*64)*192);
#pragma unroll
      for(int j=0;j<6;j++){
        int f = tid + 256*j;
        int row = f / 24, cu = f - row*24;
        *(uint4*)&sKV[row*200 + cu*8] = src[f];
      }
    }
    __syncthreads();
    f32x4 acc[3][4];
#pragma unroll
    for(int h=0;h<3;h++)
#pragma unroll
      for(int nt=0;nt<4;nt++) acc[h][nt] = f32x4{0.f,0.f,0.f,0.f};
#pragma unroll
    for(int h=0;h<3;h++)
#pragma unroll
      for(int kf=0;kf<2;kf++){
        short8 aq = qf[h][kf];
#pragma unroll
        for(int nt=0;nt<4;nt++){
          short8 bk = *(const short8*)&sKV[(nt*16 + l16)*200 + h*64 + kf*32 + h4*8];
          acc[h][nt] = __builtin_amdgcn_mfma_f32_16x16x32_bf16(aq, bk, acc[h][nt], 0,0,0);
        }
      }
    __syncthreads();   // all waves done reading K before V overwrite
    {
      const short* vb_ = vt + (size_t)b*192*832 + ks*64;
#pragma unroll
      for(int j=0;j<6;j++){
        int f = tid + 256*j;
        int cc = f >> 3, u = f & 7;
        *(uint4*)&sKV[cc*72 + u*8] = *(const uint4*)(vb_ + (size_t)cc*832 + u*8);
      }
    }
    __syncthreads();
    bool full = (ks < 12);
#pragma unroll
    for(int nt=0;nt<4;nt++){
      bool valid = full || (ks*64 + nt*16 + l16) < 784;
#pragma unroll
      for(int r=0;r<4;r++){
        float s0 = acc[0][nt][r], s1 = acc[1][nt][r], s2 = acc[2][nt][r];
        float pn[3];
#pragma unroll
        for(int g=0;g<3;g++){
          float sm = fmaf(pm[0][g], s0, fmaf(pm[1][g], s1, pm[2][g]*s2));
          float e = valid ? __expf(sm) : 0.f;
          pn[g] = e * Zp[g][r];
        }
#pragma unroll
        for(int gp=0;gp<3;gp++){
          float wp = fmaf(po[0][gp], pn[0], fmaf(po[1][gp], pn[1], po[2][gp]*pn[2]));
          sP[w][gp][h4*4+r][nt*16+l16] = f2bf(wp);
        }
      }
    }
#pragma unroll
    for(int gp=0;gp<3;gp++)
#pragma unroll
      for(int kf=0;kf<2;kf++){
        short8 pa = *(const short8*)&sP[w][gp][l16][kf*32 + h4*8];
#pragma unroll
        for(int nt=0;nt<4;nt++){
          short8 vb = *(const short8*)&sKV[(gp*64 + nt*16 + l16)*72 + kf*32 + h4*8];
          U[gp][nt] = __builtin_amdgcn_mfma_f32_16x16x32_bf16(pa, vb, U[gp][nt], 0,0,0);
        }
      }
  }
#pragma unroll
  for(int gp=0;gp<3;gp++)
#pragma unroll
    for(int nt=0;nt<4;nt++){
      int col = gp*64 + nt*16 + l16;
#pragma unroll
      for(int r=0;r<4;r++){
        sb[((size_t)b*3136 + lw + h4*4 + r)*192 + col] = f2bf(U[gp][nt][r]);
      }
    }
}

extern "C" void kernel_launch(void* const* d_in, const int* in_sizes, int n_in,
                              void* d_out, int out_size, void* d_ws, size_t ws_size,
                              hipStream_t stream){
  (void)in_sizes; (void)n_in; (void)out_size; (void)ws_size;
  const float* inq  = (const float*)d_in[0];
  const float* inkv = (const float*)d_in[1];
  const float* dwq  = (const float*)d_in[2];
  const float* dwk  = (const float*)d_in[3];
  const float* dwv  = (const float*)d_in[4];
  const float* scq  = (const float*)d_in[5];  const float* ofq = (const float*)d_in[6];
  const float* sck  = (const float*)d_in[7];  const float* ofk = (const float*)d_in[8];
  const float* scv  = (const float*)d_in[9];  const float* ofv = (const float*)d_in[10];
  const float* pwq  = (const float*)d_in[11];
  const float* pwk  = (const float*)d_in[12];
  const float* pwv  = (const float*)d_in[13];
  const float* pre  = (const float*)d_in[14];
  const float* post = (const float*)d_in[15];
  const float* wout = (const float*)d_in[16];

  char* ws = (char*)d_ws;
  size_t off = 0;
  auto alloc = [&](size_t bytes)->void*{ void* p = ws + off; off += (bytes + 255) & ~(size_t)255; return p; };
  short*  dqb  = (short*) alloc(50176ull*192*2);
  short*  dkb  = (short*) alloc(12544ull*192*2);
  short*  dvb  = (short*) alloc(12544ull*192*2);
  short*  qb   = (short*) alloc(50176ull*192*2);
  short*  kbuf = (short*) alloc(16ull*832*192*2);
  short*  vtb  = (short*) alloc(16ull*192*832*2);
  short*  sbuf = (short*) alloc(50176ull*192*2);
  float2* pq   = (float2*)alloc(896ull*192*sizeof(float2));
  float2* pk   = (float2*)alloc(448ull*192*sizeof(float2));
  float2* pv   = (float2*)alloc(448ull*192*sizeof(float2));
  short*  Wt   = (short*) alloc(4ull*192*192*2);
  float*  bias = (float*) alloc(4ull*192*4);

  (void)hipMemsetAsync(kbuf, 0, 16ull*832*192*2, stream);   // zero-pad Lk 784->832
  (void)hipMemsetAsync(vtb,  0, 16ull*192*832*2, stream);

  k_dw1<<<896, 384, 0, stream>>>(inq, dwq, dqb, pq);
  k_dw2<<<448, 384, 0, stream>>>(inkv, dwk, dwv, dkb, dvb, pk, pv);
  k_fin<<<4, 192, 0, stream>>>(pq, pk, pv, scq, ofq, sck, ofk, scv, ofv, pwq, pwk, pwv, wout, Wt, bias);
  k_gemm<0><<<784, 256, 0, stream>>>(dqb, Wt,            bias,       (void*)qb);
  k_gemm<1><<<196, 256, 0, stream>>>(dkb, Wt + 36864,    bias + 192, (void*)kbuf);
  k_gemm<2><<<196, 256, 0, stream>>>(dvb, Wt + 2*36864,  bias + 384, (void*)vtb);
  k_attn<<<784, 256, 0, stream>>>(qb, kbuf, vtb, pre, post, sbuf);
  k_gemm<3><<<784, 256, 0, stream>>>(sbuf, Wt + 3*36864, bias + 576, d_out);
}

// Round 2
// 310.627 us; speedup vs baseline: 1.7295x; 1.7295x over previous
//
#include <hip/hip_runtime.h>

using short8 = __attribute__((ext_vector_type(8))) short;
using f32x4  = __attribute__((ext_vector_type(4))) float;

__device__ __forceinline__ short f2bf(float f){
  unsigned u = __float_as_uint(f);
  unsigned r = (u + 0x7FFFu + ((u >> 16) & 1u)) >> 16;
  return (short)r;
}

// ---------------- depthwise 3x3 stride-1 (q) + stats partials, rolling window ----------------
__global__ __launch_bounds__(384) void k_dw1(const float* __restrict__ in, const float* __restrict__ wq,
                                             short* __restrict__ dqb, float2* __restrict__ part){
  int bid = blockIdx.x; int b = bid / 56, oh = bid % 56; int t = threadIdx.x;
  int c = t % 192, strip = t / 192;            // strip 0: ow 0..27, strip 1: ow 28..55
  float w[9];
#pragma unroll
  for(int i=0;i<9;i++) w[i] = wq[i*192 + c];
  const float* inb = in + (size_t)b*56*56*192;
  const float* rp[3]; bool rv[3];
#pragma unroll
  for(int kh=0;kh<3;kh++){
    int ih = oh + kh - 1;
    rv[kh] = (ih >= 0 && ih < 56);
    rp[kh] = inb + (size_t)(rv[kh] ? ih : 0)*56*192 + c;
  }
  auto ldc = [&](int kh, int iw)->float{
    return (rv[kh] && iw >= 0 && iw < 56) ? rp[kh][iw*192] : 0.f;
  };
  int ow0 = strip*28;
  float x0[3], x1[3];
#pragma unroll
  for(int kh=0;kh<3;kh++){ x0[kh] = ldc(kh, ow0-1); x1[kh] = ldc(kh, ow0); }
  float lsum = 0.f, lsq = 0.f;
  size_t orow = ((size_t)b*3136 + (size_t)oh*56)*192;
#pragma unroll 1
  for(int j=0;j<28;j++){
    int ow = ow0 + j;
    float x2[3];
#pragma unroll
    for(int kh=0;kh<3;kh++) x2[kh] = ldc(kh, ow+1);
    float acc = 0.f;
#pragma unroll
    for(int kh=0;kh<3;kh++){
      acc = fmaf(x0[kh], w[kh*3+0], acc);
      acc = fmaf(x1[kh], w[kh*3+1], acc);
      acc = fmaf(x2[kh], w[kh*3+2], acc);
    }
    dqb[orow + (size_t)ow*192 + c] = f2bf(acc);
    lsum += acc; lsq = fmaf(acc, acc, lsq);
#pragma unroll
    for(int kh=0;kh<3;kh++){ x0[kh] = x1[kh]; x1[kh] = x2[kh]; }
  }
  __shared__ float red[2][384];
  red[0][t] = lsum; red[1][t] = lsq;
  __syncthreads();
  if(t < 192){
    float2 o; o.x = lsum + red[0][t+192]; o.y = lsq + red[1][t+192];
    part[(size_t)bid*192 + t] = o;
  }
}

// ---------------- depthwise 3x3 stride-2 (k and v) + stats partials, rolling window ----------------
__global__ __launch_bounds__(384) void k_dw2(const float* __restrict__ in, const float* __restrict__ wk,
                                             const float* __restrict__ wv, short* __restrict__ dkb,
                                             short* __restrict__ dvb, float2* __restrict__ partk,
                                             float2* __restrict__ partv){
  int bid = blockIdx.x; int b = bid / 28, oh = bid % 28; int t = threadIdx.x;
  int c = t % 192, strip = t / 192;            // strip 0: ow 0..13, strip 1: ow 14..27
  float wkr[9], wvr[9];
#pragma unroll
  for(int i=0;i<9;i++){ wkr[i] = wk[i*192 + c]; wvr[i] = wv[i*192 + c]; }
  const float* inb = in + (size_t)b*56*56*192;
  const float* rp[3]; bool rv[3];
#pragma unroll
  for(int kh=0;kh<3;kh++){
    int ih = 2*oh + kh;                        // SAME stride-2: pad_lo = 0
    rv[kh] = (ih < 56);
    rp[kh] = inb + (size_t)(rv[kh] ? ih : 0)*56*192 + c;
  }
  auto ldc = [&](int kh, int iw)->float{
    return (rv[kh] && iw < 56) ? rp[kh][iw*192] : 0.f;
  };
  int ow0 = strip*14;
  float xp[3];
#pragma unroll
  for(int kh=0;kh<3;kh++) xp[kh] = ldc(kh, 2*ow0);
  float ksum=0.f, ksq=0.f, vsum=0.f, vsq=0.f;
  size_t orow = ((size_t)b*784 + (size_t)oh*28)*192;
#pragma unroll 1
  for(int j=0;j<14;j++){
    int ow = ow0 + j;
    float xm[3], xn[3];
#pragma unroll
    for(int kh=0;kh<3;kh++){ xm[kh] = ldc(kh, 2*ow+1); xn[kh] = ldc(kh, 2*ow+2); }
    float ak = 0.f, av = 0.f;
#pragma unroll
    for(int kh=0;kh<3;kh++){
      ak = fmaf(xp[kh], wkr[kh*3+0], ak); ak = fmaf(xm[kh], wkr[kh*3+1], ak); ak = fmaf(xn[kh], wkr[kh*3+2], ak);
      av = fmaf(xp[kh], wvr[kh*3+0], av); av = fmaf(xm[kh], wvr[kh*3+1], av); av = fmaf(xn[kh], wvr[kh*3+2], av);
    }
    dkb[orow + (size_t)ow*192 + c] = f2bf(ak);
    dvb[orow + (size_t)ow*192 + c] = f2bf(av);
    ksum += ak; ksq = fmaf(ak, ak, ksq);
    vsum += av; vsq = fmaf(av, av, vsq);
#pragma unroll
    for(int kh=0;kh<3;kh++) xp[kh] = xn[kh];
  }
  __shared__ float red[4][384];
  red[0][t]=ksum; red[1][t]=ksq; red[2][t]=vsum; red[3][t]=vsq;
  __syncthreads();
  if(t < 192){
    float2 a; a.x = ksum + red[0][t+192]; a.y = ksq + red[1][t+192];
    partk[(size_t)bid*192 + t] = a;
    float2 o; o.x = vsum + red[2][t+192]; o.y = vsq + red[3][t+192];
    partv[(size_t)bid*192 + t] = o;
  }
}

// ---------------- stage-1 reduce of stats partials (896/448 rows -> 8/4 rows) ----------------
__global__ __launch_bounds__(192) void k_red(const float2* __restrict__ pq, const float2* __restrict__ pk,
                                             const float2* __restrict__ pv, float2* __restrict__ oq,
                                             float2* __restrict__ ok2, float2* __restrict__ ov2){
  int blk = blockIdx.x, t = threadIdx.x;
  const float2* src; float2* dst;
  if(blk < 8){ src = pq + (size_t)blk*112*192;      dst = oq  + (size_t)blk*192; }
  else if(blk < 12){ src = pk + (size_t)(blk-8)*112*192;  dst = ok2 + (size_t)(blk-8)*192; }
  else { src = pv + (size_t)(blk-12)*112*192; dst = ov2 + (size_t)(blk-12)*192; }
  float s=0.f, q=0.f;
#pragma unroll 8
  for(int i=0;i<112;i++){ float2 v = src[(size_t)i*192 + t]; s += v.x; q += v.y; }
  float2 o; o.x=s; o.y=q; dst[t] = o;
}

// ---------------- finalize stats; fold BN + scale into transposed bf16 weights ----------------
__global__ __launch_bounds__(192) void k_fin(const float2* __restrict__ pq, const float2* __restrict__ pk,
                                             const float2* __restrict__ pv,
                                             const float* __restrict__ sq, const float* __restrict__ oq,
                                             const float* __restrict__ sk, const float* __restrict__ ok,
                                             const float* __restrict__ sv, const float* __restrict__ ov,
                                             const float* __restrict__ pwq, const float* __restrict__ pwk,
                                             const float* __restrict__ pwv, const float* __restrict__ wout,
                                             short* __restrict__ Wt, float* __restrict__ bias){
  int p = blockIdx.x, t = threadIdx.x;
  __shared__ float aS[192], bS[192];
  if(p < 3){
    const float2* part = (p==0)?pq:((p==1)?pk:pv);
    int nb = (p==0)?8:4;
    float N = (p==0)?50176.f:12544.f;
    const float* sc = (p==0)?sq:((p==1)?sk:sv);
    const float* of = (p==0)?oq:((p==1)?ok:ov);
    float s=0.f, q2=0.f;
#pragma unroll
    for(int i=0;i<8;i++){ if(i<nb){ float2 v = part[(size_t)i*192 + t]; s += v.x; q2 += v.y; } }
    float mean = s / N;
    float var  = q2 / N - mean*mean;
    float a  = rsqrtf(var + 1e-5f) * sc[t];
    float bv = of[t] - mean*a;
    aS[t] = a; bS[t] = bv;
    __syncthreads();
    const float* pw = (p==0)?pwq:((p==1)?pwk:pwv);
    float qs = (p==0) ? 0.125f : 1.0f;   // fold 1/sqrt(64) into q
    float bacc = 0.f;
    for(int cc=0; cc<192; cc++){
      float wv_ = pw[cc*192 + t];
      bacc = fmaf(bS[cc], wv_, bacc);
      Wt[((size_t)p*192 + t)*192 + cc] = f2bf(aS[cc]*wv_*qs);
    }
    bias[p*192 + t] = bacc * qs;
  } else {
    for(int cc=0; cc<192; cc++) Wt[((size_t)3*192 + t)*192 + cc] = f2bf(wout[cc*192 + t]);
    bias[3*192 + t] = 0.f;
  }
}

// ---------------- bf16 MFMA GEMM: [M,192] @ (Wt^T) + bias; per-mode epilogue ----------------
template<int MODE>
__global__ __launch_bounds__(256) void k_gemm(const short* __restrict__ A, const short* __restrict__ Wt,
                                              const float* __restrict__ bias, void* __restrict__ outp){
  int w = threadIdx.x >> 6, L = threadIdx.x & 63, l16 = L & 15, h4 = L >> 4;
  int row0 = blockIdx.x*64 + w*16;
  short8 af[6];
  const short8* arow = (const short8*)(A + (size_t)(row0 + l16)*192);
#pragma unroll
  for(int kf=0;kf<6;kf++) af[kf] = arow[kf*4 + h4];
  f32x4 acc[12];
#pragma unroll
  for(int i=0;i<12;i++) acc[i] = f32x4{0.f,0.f,0.f,0.f};
#pragma unroll
  for(int nt=0;nt<12;nt++){
    const short8* wrow = (const short8*)(Wt + (size_t)(nt*16 + l16)*192);
#pragma unroll
    for(int kf=0;kf<6;kf++){
      short8 bf = wrow[kf*4 + h4];
      acc[nt] = __builtin_amdgcn_mfma_f32_16x16x32_bf16(af[kf], bf, acc[nt], 0,0,0);
    }
  }
#pragma unroll
  for(int nt=0;nt<12;nt++){
    int col = nt*16 + l16;
    float bv = (MODE==3) ? 0.f : bias[col];
#pragma unroll
    for(int r=0;r<4;r++){
      int row = row0 + h4*4 + r;
      float v = acc[nt][r] + bv;
      if(MODE==0){
        ((short*)outp)[(size_t)row*192 + col] = f2bf(v);
      } else if(MODE==1){
        int b = row/784, kk = row - b*784;
        ((short*)outp)[((size_t)b*832 + kk)*192 + col] = f2bf(v);
      } else if(MODE==2){
        int b = row/784, kk = row - b*784;
        ((short*)outp)[((size_t)(b*192 + col))*832 + kk] = f2bf(v);
      } else {
        ((float*)outp)[(size_t)row*192 + col] = v;
      }
    }
  }
}

// ---------------- fused talking-heads attention: SINGLE PASS ----------------
// T[g][gp] = sum_k exp_g(k) * V_gp(k)   (unnormalized), Z_g tracked per row.
// Final: U[gp] = sum_g post[g][gp] * (1/Z_g) * T[g][gp].
// grid 784 = 16 b x 49 l-tiles(64); block 256 = 4 waves, wave -> 16 l rows.
__global__ __launch_bounds__(256, 2) void k_attn(const short* __restrict__ qb, const short* __restrict__ kb,
                                                 const short* __restrict__ vt, const float* __restrict__ pre,
                                                 const float* __restrict__ post, short* __restrict__ sb){
  __shared__ __align__(16) short sK[32*200];        // K tile [32 k][192+pad]
  __shared__ __align__(16) short sV[192*40];        // V tile [192 c][32 k + pad]
  __shared__ __align__(16) short sP[4][3][16][40];  // per-wave exp_g (bf16), [rows][32k+pad]
  int bx = blockIdx.x; int b = bx / 49, lt = bx - b*49;
  int tid = threadIdx.x; int w = tid >> 6, L = tid & 63, l16 = L & 15, h4 = L >> 4;
  int lw = lt*64 + w*16;
  float pm[3][3];
#pragma unroll
  for(int h=0;h<3;h++)
#pragma unroll
    for(int g=0;g<3;g++) pm[h][g] = pre[h*3+g];

  short8 qf[3][2];
  const short8* qrow = (const short8*)(qb + ((size_t)b*3136 + lw + l16)*192);
#pragma unroll
  for(int h=0;h<3;h++)
#pragma unroll
    for(int kf=0;kf<2;kf++) qf[h][kf] = qrow[h*8 + kf*4 + h4];

  f32x4 T[3][3][4];      // [g][gp][nt over d]
#pragma unroll
  for(int g=0;g<3;g++)
#pragma unroll
    for(int gp=0;gp<3;gp++)
#pragma unroll
      for(int nt=0;nt<4;nt++) T[g][gp][nt] = f32x4{0.f,0.f,0.f,0.f};
  float Zp[3][4];
#pragma unroll
  for(int g=0;g<3;g++)
#pragma unroll
    for(int r=0;r<4;r++) Zp[g][r] = 0.f;

#pragma unroll 1
  for(int ks=0; ks<26; ks++){
    __syncthreads();
    {
      const uint4* ksrc = (const uint4*)(kb + ((size_t)b*832 + ks*32)*192);
#pragma unroll
      for(int j=0;j<3;j++){
        int f = tid + 256*j;
        int row = f / 24, cu = f - row*24;
        *(uint4*)&sK[row*200 + cu*8] = ksrc[f];
      }
      const short* vsrc = vt + (size_t)b*192*832 + ks*32;
#pragma unroll
      for(int j=0;j<3;j++){
        int f = tid + 256*j;
        int cc = f >> 2, u = f & 3;
        *(uint4*)&sV[cc*40 + u*8] = *(const uint4*)(vsrc + (size_t)cc*832 + u*8);
      }
    }
    __syncthreads();
    // QK^T for this 32-k tile
    f32x4 acc[3][2];
#pragma unroll
    for(int h=0;h<3;h++)
#pragma unroll
      for(int nt=0;nt<2;nt++) acc[h][nt] = f32x4{0.f,0.f,0.f,0.f};
#pragma unroll
    for(int h=0;h<3;h++)
#pragma unroll
      for(int kf=0;kf<2;kf++){
        short8 aq = qf[h][kf];
#pragma unroll
        for(int nt=0;nt<2;nt++){
          short8 bk = *(const short8*)&sK[(nt*16 + l16)*200 + h*64 + kf*32 + h4*8];
          acc[h][nt] = __builtin_amdgcn_mfma_f32_16x16x32_bf16(aq, bk, acc[h][nt], 0,0,0);
        }
      }
    // pre-mix + exp (unnormalized), write to per-wave sP
#pragma unroll
    for(int nt=0;nt<2;nt++){
      bool valid = (ks*32 + nt*16 + l16) < 784;
#pragma unroll
      for(int r=0;r<4;r++){
        float s0 = acc[0][nt][r], s1 = acc[1][nt][r], s2 = acc[2][nt][r];
#pragma unroll
        for(int g=0;g<3;g++){
          float sm = fmaf(pm[0][g], s0, fmaf(pm[1][g], s1, pm[2][g]*s2));
          float e = valid ? __expf(sm) : 0.f;
          Zp[g][r] += e;
          sP[w][g][h4*4+r][nt*16+l16] = f2bf(e);
        }
      }
    }
    // PV accumulate into T[g][gp]  (within-wave sP dependency; no barrier needed)
    short8 pa[3];
#pragma unroll
    for(int g=0;g<3;g++) pa[g] = *(const short8*)&sP[w][g][l16][h4*8];
#pragma unroll
    for(int gp=0;gp<3;gp++)
#pragma unroll
      for(int nt=0;nt<4;nt++){
        short8 vb = *(const short8*)&sV[(gp*64 + nt*16 + l16)*40 + h4*8];
#pragma unroll
        for(int g=0;g<3;g++)
          T[g][gp][nt] = __builtin_amdgcn_mfma_f32_16x16x32_bf16(pa[g], vb, T[g][gp][nt], 0,0,0);
      }
  }

  // Z reduce across the 16 k-lanes (within 16-lane groups)
  float invZ[3][4];
#pragma unroll
  for(int g=0;g<3;g++)
#pragma unroll
    for(int r=0;r<4;r++){
      float z = Zp[g][r];
      z += __shfl_xor(z, 1); z += __shfl_xor(z, 2); z += __shfl_xor(z, 4); z += __shfl_xor(z, 8);
      invZ[g][r] = 1.f / z;
    }
  float po[3][3];
#pragma unroll
  for(int g=0;g<3;g++)
#pragma unroll
    for(int gp=0;gp<3;gp++) po[g][gp] = post[g*3+gp];

#pragma unroll
  for(int gp=0;gp<3;gp++){
    float cg[3][4];
#pragma unroll
    for(int g=0;g<3;g++)
#pragma unroll
      for(int r=0;r<4;r++) cg[g][r] = po[g][gp] * invZ[g][r];
#pragma unroll
    for(int nt=0;nt<4;nt++){
      int col = gp*64 + nt*16 + l16;
#pragma unroll
      for(int r=0;r<4;r++){
        float u = fmaf(cg[0][r], T[0][gp][nt][r], fmaf(cg[1][r], T[1][gp][nt][r], cg[2][r]*T[2][gp][nt][r]));
        sb[((size_t)b*3136 + lw + h4*4 + r)*192 + col] = f2bf(u);
      }
    }
  }
}

extern "C" void kernel_launch(void* const* d_in, const int* in_sizes, int n_in,
                              void* d_out, int out_size, void* d_ws, size_t ws_size,
                              hipStream_t stream){
  (void)in_sizes; (void)n_in; (void)out_size; (void)ws_size;
  const float* inq  = (const float*)d_in[0];
  const float* inkv = (const float*)d_in[1];
  const float* dwq  = (const float*)d_in[2];
  const float* dwk  = (const float*)d_in[3];
  const float* dwv  = (const float*)d_in[4];
  const float* scq  = (const float*)d_in[5];  const float* ofq = (const float*)d_in[6];
  const float* sck  = (const float*)d_in[7];  const float* ofk = (const float*)d_in[8];
  const float* scv  = (const float*)d_in[9];  const float* ofv = (const float*)d_in[10];
  const float* pwq  = (const float*)d_in[11];
  const float* pwk  = (const float*)d_in[12];
  const float* pwv  = (const float*)d_in[13];
  const float* pre  = (const float*)d_in[14];
  const float* post = (const float*)d_in[15];
  const float* wout = (const float*)d_in[16];

  char* ws = (char*)d_ws;
  size_t off = 0;
  auto alloc = [&](size_t bytes)->void*{ void* p = ws + off; off += (bytes + 255) & ~(size_t)255; return p; };
  short*  dqb  = (short*) alloc(50176ull*192*2);
  short*  dkb  = (short*) alloc(12544ull*192*2);
  short*  dvb  = (short*) alloc(12544ull*192*2);
  short*  qb   = (short*) alloc(50176ull*192*2);
  short*  kbuf = (short*) alloc(16ull*832*192*2);
  short*  vtb  = (short*) alloc(16ull*192*832*2);
  short*  sbuf = (short*) alloc(50176ull*192*2);
  float2* pq   = (float2*)alloc(896ull*192*sizeof(float2));
  float2* pk   = (float2*)alloc(448ull*192*sizeof(float2));
  float2* pv   = (float2*)alloc(448ull*192*sizeof(float2));
  float2* pq2  = (float2*)alloc(8ull*192*sizeof(float2));
  float2* pk2  = (float2*)alloc(4ull*192*sizeof(float2));
  float2* pv2  = (float2*)alloc(4ull*192*sizeof(float2));
  short*  Wt   = (short*) alloc(4ull*192*192*2);
  float*  bias = (float*) alloc(4ull*192*4);

  (void)hipMemsetAsync(kbuf, 0, 16ull*832*192*2, stream);   // zero-pad Lk 784->832
  (void)hipMemsetAsync(vtb,  0, 16ull*192*832*2, stream);

  k_dw1<<<896, 384, 0, stream>>>(inq, dwq, dqb, pq);
  k_dw2<<<448, 384, 0, stream>>>(inkv, dwk, dwv, dkb, dvb, pk, pv);
  k_red<<<16, 192, 0, stream>>>(pq, pk, pv, pq2, pk2, pv2);
  k_fin<<<4, 192, 0, stream>>>(pq2, pk2, pv2, scq, ofq, sck, ofk, scv, ofv, pwq, pwk, pwv, wout, Wt, bias);
  k_gemm<0><<<784, 256, 0, stream>>>(dqb, Wt,            bias,       (void*)qb);
  k_gemm<1><<<196, 256, 0, stream>>>(dkb, Wt + 36864,    bias + 192, (void*)kbuf);
  k_gemm<2><<<196, 256, 0, stream>>>(dvb, Wt + 2*36864,  bias + 384, (void*)vtb);
  k_attn<<<784, 256, 0, stream>>>(qb, kbuf, vtb, pre, post, sbuf);
  k_gemm<3><<<784, 256, 0, stream>>>(sbuf, Wt + 3*36864, bias + 576, d_out);
}